// Round 15
// baseline (69.707 us; speedup 1.0000x reference)
//
#include <hip/hip_runtime.h>

#define HOLE_P 0.05f
#define TW 64
#define TH 64
#define HALO 8
#define PRW 88         // padded row: 3 pad + guard + 80 content + guard + 3 pad
#define PRH 82         // guard + 80 content rows + guard
#define PLN 7216       // PRW*PRH
#define PWORDS 1804
#define QCAP 1536      // worklist capacity (expected ~440, ~27 sigma margin)

// Kernel 1: pack invalid = (hole_u < p) into bitmask, 8 px per byte, flat [c][y][x/8]
__global__ void k_mask(const float* __restrict__ hole_u, unsigned char* __restrict__ inv_mask) {
    int t = blockIdx.x * blockDim.x + threadIdx.x;    // 0 .. 2M-1
    const float* base = hole_u + (size_t)t * 8;
    float4 a = *reinterpret_cast<const float4*>(base);
    float4 b = *reinterpret_cast<const float4*>(base + 4);
    unsigned int m = (a.x < HOLE_P ? 1u : 0u)  | (a.y < HOLE_P ? 2u : 0u)  |
                     (a.z < HOLE_P ? 4u : 0u)  | (a.w < HOLE_P ? 8u : 0u)  |
                     (b.x < HOLE_P ? 16u : 0u) | (b.y < HOLE_P ? 32u : 0u) |
                     (b.z < HOLE_P ? 64u : 0u) | (b.w < HOLE_P ? 128u : 0u);
    inv_mask[t] = (unsigned char)m;
}

// Kernel 2: u_small[i][j] = OR over channels of invalid[c][2i][2j]
__global__ void k_us(const unsigned char* __restrict__ inv_mask, unsigned char* __restrict__ u_small) {
    int t = blockIdx.x * blockDim.x + threadIdx.x;    // 0 .. 65535
    int i  = t >> 7;
    int jb = t & 127;
    const unsigned char* p = inv_mask + (i << 8) + jb;
    unsigned int b = 0;
#pragma unroll
    for (int c = 0; c < 16; ++c) b |= p[c * 131072];
    unsigned int o = (b & 1u) | (((b >> 2) & 1u) << 8) | (((b >> 4) & 1u) << 16) | (((b >> 6) & 1u) << 24);
    *reinterpret_cast<unsigned int*>(u_small + i * 512 + jb * 4) = o;
}

// Kernel 3: d_small = cross-dilate(u_small), zero pad
__global__ void k_dil(const unsigned char* __restrict__ u_small, unsigned char* __restrict__ d_small) {
    int g = blockIdx.x * blockDim.x + threadIdx.x;
    int i = g >> 9, j = g & 511;
    unsigned char d = u_small[g];
    if (i > 0)   d |= u_small[g - 512];
    if (i < 511) d |= u_small[g + 512];
    if (j > 0)   d |= u_small[g - 1];
    if (j < 511) d |= u_small[g + 1];
    d_small[g] = d;
}

// Halo group index h (0..575) -> (row 0..79, col-group 0..19) of 80x80 content.
__device__ __forceinline__ void halo_map(int h, int& ly, int& lxg) {
    if (h < 160)      { ly = h / 20;                lxg = h - (h / 20) * 20; }
    else if (h < 320) { int t2 = h - 160; ly = 72 + t2 / 20; lxg = t2 - (t2 / 20) * 20; }
    else              { int t2 = h - 320; ly = 8 + (t2 >> 2); int q = t2 & 3; lxg = q < 2 ? q : q + 16; }
}

// State-word encode from src/invalid nibbles (bit i -> byte i).
__device__ __forceinline__ unsigned int enc_w(unsigned int src, unsigned int nib) {
    return ((src * 0x204081u) & 0x01010101u) | (((nib * 0x204081u) & 0x01010101u) << 7);
}

// Reciprocal of cnt in {1,2,3,4} via selects.
__device__ __forceinline__ float rcp_cnt(int cn) {
    float lo = (cn == 1) ? 1.0f : 0.5f;
    float hi = (cn == 3) ? (1.0f / 3.0f) : 0.25f;
    return (cn <= 2) ? lo : hi;
}

// Worklist Jacobi: 1 px/lane; states monotone; pending/stationary exits.
__device__ __forceinline__ void wl_jacobi(
    float* v, unsigned char* w, const unsigned short* q, int n,
    int* chgf, int* pendf, int tid)
{
    for (int it = 0; it < 8; ++it) {
        int chg = 0, pend = 0;
        unsigned int thr = (unsigned int)it;
        for (int i = tid; i < n; i += 512) {
            unsigned int e = q[i];
            int p = e & 0x1fffu;
            if (w[p] & 0x7fu) continue;            // already filled
            unsigned int qu = w[p - PRW] & 0x7fu;
            unsigned int qd = w[p + PRW] & 0x7fu;
            unsigned int ql = w[p - 1]   & 0x7fu;
            unsigned int qr = w[p + 1]   & 0x7fu;
            bool su = (qu - 1u) <= thr, sd = (qd - 1u) <= thr;
            bool sl = (ql - 1u) <= thr, sr = (qr - 1u) <= thr;
            float s = (su ? v[p - PRW] : 0.0f) + (sd ? v[p + PRW] : 0.0f)
                    + (sl ? v[p - 1]   : 0.0f) + (sr ? v[p + 1]   : 0.0f);
            int cn = (int)su + (int)sd + (int)sl + (int)sr;
            if (cn > 0) {
                v[p] = s * rcp_cnt(cn);            // reads gated by old states
                w[p] = (unsigned char)((((e >> 14) & 1u) << 7) | (unsigned int)(it + 2));
                chg = 1;
            } else {
                pend |= (int)((e >> 15) & 1u);
            }
        }
        if (chg)  chgf[it] = 1;                    // benign all-write-1 races
        if (pend) pendf[it] = 1;
        __syncthreads();
        if (chgf[it] == 0 || pendf[it] == 0) break;
    }
}

// Dense fallback (worklist overflow, ~never): full sweeps, exact per-byte test.
__device__ __forceinline__ void dense_sweep(
    float* v, unsigned char* w, unsigned int* w32, int* chgf, int tid)
{
    for (int it = 0; it < 8; ++it) {
        int chg = 0;
        unsigned int thr = (unsigned int)it;
        for (int wp = tid; wp < PWORDS; wp += 512) {
            unsigned int cw = w32[wp];
            unsigned int st = cw & 0x7f7f7f7fu;
            if ((((st - 0x01010101u) & ~st) & 0x80808080u) == 0u) continue;
            int p0 = wp * 4;
#pragma unroll
            for (int b = 0; b < 4; ++b) {
                if (((st >> (8 * b)) & 0x7fu) != 0u) continue;
                int p = p0 + b;
                unsigned int qu = w[p - PRW] & 0x7fu, qd = w[p + PRW] & 0x7fu;
                unsigned int ql = w[p - 1] & 0x7fu,   qr = w[p + 1] & 0x7fu;
                bool su = (qu - 1u) <= thr, sd = (qd - 1u) <= thr;
                bool sl = (ql - 1u) <= thr, sr = (qr - 1u) <= thr;
                float s = (su ? v[p - PRW] : 0.0f) + (sd ? v[p + PRW] : 0.0f)
                        + (sl ? v[p - 1]   : 0.0f) + (sr ? v[p + 1]   : 0.0f);
                int cn = (int)su + (int)sd + (int)sl + (int)sr;
                if (cn > 0) {
                    v[p] = s * rcp_cnt(cn);
                    w[p] = (unsigned char)(((cw >> (8 * b)) & 0x80u) | (unsigned int)(it + 2));
                    chg = 1;
                }
            }
        }
        if (chg) chgf[it] = 1;
        __syncthreads();
        if (chgf[it] == 0) break;
    }
}

// Kernel 4: 2-tile software pipeline. Each block processes channels c and c+8
// at the same (tx,ty): geometry AND d_small values are tile-invariant (d_small
// is the channel union). Tile B's x/mask loads are issued right after tile A's
// encode (A's regs die there) and fly under A's worklist+Jacobi+epilogue.
// Grid 2048 = 4 blocks/CU resident + one full replacement round (R12 lesson:
// never make grid == co-residency). Per-tile logic is R14's verbatim.
__global__ __launch_bounds__(512, 8) void k_fill(
    const float* __restrict__ x, const unsigned char* __restrict__ inv_mask,
    const unsigned char* __restrict__ d_small, float* __restrict__ out)
{
    __shared__ __align__(16) float v[PLN];
    __shared__ unsigned int w32[PWORDS];
    __shared__ unsigned short q[QCAP];
    __shared__ int qn;
    __shared__ int chgf[8], pendf[8];
    unsigned char* w = (unsigned char*)w32;

    const int tid = threadIdx.x;
    const int lane = tid & 63;
    const int tx = blockIdx.x, ty = blockIdx.y;
    const int cA = blockIdx.z;                       // 0..7; tile B = cA+8
    const int by0 = ty * TH, bx0 = tx * TW;
    const bool cornerTile = ((tx == 0) | (tx == 15)) & ((ty == 0) | (ty == 15));

    const float* xcA = x + cA * 1048576;
    const float* xcB = xcA + 8 * 1048576;
    const unsigned char* mcA = inv_mask + cA * 131072;
    const unsigned char* mcB = mcA + 8 * 131072;
    float* ocA = out + cA * 1048576;
    float* ocB = ocA + 8 * 1048576;

    // ---- tile-invariant geometry ----
    const int r0 = tid >> 4, cg0 = tid & 15;
    const int gy0 = by0 + r0, gx0 = bx0 + cg0 * 4, gy1 = gy0 + 32;
    const int gi0 = gy0 * 1024 + gx0, gi1 = gy1 * 1024 + gx0;
    const int mi0 = (gy0 << 7) + (gx0 >> 3), mi1 = (gy1 << 7) + (gx0 >> 3);
    int aly, alxg, bly, blxg;
    halo_map(tid, aly, alxg);
    const bool hasB = (tid < 64);
    halo_map(hasB ? tid + 512 : 0, bly, blxg);
    const int agy = by0 - HALO + aly, agx0 = bx0 - HALO + alxg * 4;
    const int bgy = by0 - HALO + bly, bgx0 = bx0 - HALO + blxg * 4;
    const bool ain = ((unsigned)agy < 1024u) & ((unsigned)agx0 < 1024u);
    const bool bin = hasB & ((unsigned)bgy < 1024u) & ((unsigned)bgx0 < 1024u);
    const int giA = agy * 1024 + agx0, miA = (agy << 7) + (agx0 >> 3), diA = ((agy >> 1) << 9) + (agx0 >> 1);
    const int giB = bgy * 1024 + bgx0, miB = (bgy << 7) + (bgx0 >> 3), diB = ((bgy >> 1) << 9) + (bgx0 >> 1);
    const int P0i0 = (9 + r0) * PRW + 12 + cg0 * 4;
    const int P0i1 = P0i0 + 32 * PRW;
    const int P0A = (aly + 1) * PRW + 4 + alxg * 4;
    const int P0B = (bly + 1) * PRW + 4 + blxg * 4;

    // ---- tile A loads (up front, max MLP) ----
    float4 z4 = make_float4(0.f, 0.f, 0.f, 0.f);
    float4 xx0A = *reinterpret_cast<const float4*>(xcA + gi0);
    float4 xx1A = *reinterpret_cast<const float4*>(xcA + gi1);
    float4 axxA = z4, bxxA = z4;
    if (ain) axxA = *reinterpret_cast<const float4*>(xcA + giA);
    if (bin) bxxA = *reinterpret_cast<const float4*>(xcA + giB);
    unsigned int mb0A = mcA[mi0], mb1A = mcA[mi1];
    unsigned int ambA = ain ? mcA[miA] : 0u;
    unsigned int bmbA = bin ? mcA[miB] : 0u;
    // d_small: channel-independent -> load once, reuse for both tiles
    unsigned int ds0 = *reinterpret_cast<const unsigned short*>(d_small + ((gy0 >> 1) << 9) + (gx0 >> 1));
    unsigned int ds1 = *reinterpret_cast<const unsigned short*>(d_small + ((gy1 >> 1) << 9) + (gx0 >> 1));
    unsigned int dsa = ain ? *reinterpret_cast<const unsigned short*>(d_small + diA) : 0u;
    unsigned int dsb = bin ? *reinterpret_cast<const unsigned short*>(d_small + diB) : 0u;
    const unsigned int db0 = ((ds0 & 0xffu) ? 0x3u : 0u) | ((ds0 & 0xff00u) ? 0xcu : 0u);
    const unsigned int db1 = ((ds1 & 0xffu) ? 0x3u : 0u) | ((ds1 & 0xff00u) ? 0xcu : 0u);
    const unsigned int dbA = ((dsa & 0xffu) ? 0x3u : 0u) | ((dsa & 0xff00u) ? 0xcu : 0u);
    const unsigned int dbB = ((dsb & 0xffu) ? 0x3u : 0u) | ((dsb & 0xff00u) ? 0xcu : 0u);
    const unsigned int crn0 = (cornerTile && ((gy0 == 0) | (gy0 == 1023)))
                              ? ((gx0 == 0 ? 1u : 0u) | (gx0 == 1020 ? 8u : 0u)) : 0u;
    const unsigned int crn1 = (cornerTile && ((gy1 == 0) | (gy1 == 1023)))
                              ? ((gx0 == 0 ? 1u : 0u) | (gx0 == 1020 ? 8u : 0u)) : 0u;

    // ---- flags + guard ring init ----
    if (tid < 8) { chgf[tid] = 0; pendf[tid] = 0; }
    if (tid == 0) qn = 0;
    if (tid < 204) {
        int wi;
        if (tid < 22)      wi = tid;
        else if (tid < 44) wi = 81 * 22 + (tid - 22);
        else { int r = ((tid - 44) >> 1) + 1; wi = r * 22 + (((tid - 44) & 1) ? 21 : 0); }
        w32[wi] = 0x7f7f7f7fu;
    }
    __syncthreads();

    float4 xx0B, xx1B, axxB = z4, bxxB = z4;
    unsigned int mb0B, mb1B, ambB = 0u, bmbB = 0u;

#define ENCODE_TILE(MB0, MB1, AMB, BMB, XX0, XX1, AXX, BXX)                       \
    unsigned int fN0, fN1, fNA = 0, fNB = 0;                                      \
    unsigned int iN0, iN1, iNA = 0, iNB = 0;                                      \
    {                                                                             \
        unsigned int nib = ((MB0) >> (gx0 & 7)) & 0xfu;                           \
        unsigned int src = (db0 & ~nib & 0xfu) | crn0;                            \
        *reinterpret_cast<float4*>(&v[P0i0]) = (XX0);                             \
        w32[P0i0 >> 2] = enc_w(src, nib);                                         \
        fN0 = ~src & 0xfu; iN0 = nib;                                             \
    }                                                                             \
    {                                                                             \
        unsigned int nib = ((MB1) >> (gx0 & 7)) & 0xfu;                           \
        unsigned int src = (db1 & ~nib & 0xfu) | crn1;                            \
        *reinterpret_cast<float4*>(&v[P0i1]) = (XX1);                             \
        w32[P0i1 >> 2] = enc_w(src, nib);                                         \
        fN1 = ~src & 0xfu; iN1 = nib;                                             \
    }                                                                             \
    {                                                                             \
        unsigned int ww = 0x7f7f7f7fu;                                            \
        if (ain) {                                                                \
            unsigned int nib = ((AMB) >> (agx0 & 7)) & 0xfu;                      \
            unsigned int src = dbA & ~nib & 0xfu;                                 \
            ww = enc_w(src, nib);                                                 \
            fNA = ~src & 0xfu; iNA = nib;                                         \
        }                                                                         \
        *reinterpret_cast<float4*>(&v[P0A]) = (AXX);                              \
        w32[P0A >> 2] = ww;                                                       \
    }                                                                             \
    if (hasB) {                                                                   \
        unsigned int ww = 0x7f7f7f7fu;                                            \
        if (bin) {                                                                \
            unsigned int nib = ((BMB) >> (bgx0 & 7)) & 0xfu;                      \
            unsigned int src = dbB & ~nib & 0xfu;                                 \
            ww = enc_w(src, nib);                                                 \
            fNB = ~src & 0xfu; iNB = nib;                                         \
        }                                                                         \
        *reinterpret_cast<float4*>(&v[P0B]) = (BXX);                              \
        w32[P0B >> 2] = ww;                                                       \
    }

#define BUILD_RUN_STORE(MC, OC, XX0, XX1)                                         \
    {                                                                             \
        int cnt = __popc(fN0) + __popc(fN1) + __popc(fNA) + __popc(fNB);          \
        int xsum = cnt;                                                           \
        _Pragma("unroll")                                                         \
        for (int d = 1; d < 64; d <<= 1) {                                        \
            int y = __shfl_up(xsum, d, 64);                                       \
            if (lane >= d) xsum += y;                                             \
        }                                                                         \
        int base = 0;                                                             \
        if (lane == 63) base = atomicAdd(&qn, xsum);                              \
        base = __shfl(base, 63, 64);                                              \
        int idx = base + (xsum - cnt);                                            \
        PUSH(fN0, iN0, fN0 & iN0, P0i0)                                           \
        PUSH(fN1, iN1, fN1 & iN1, P0i1)                                           \
        PUSH(fNA, iNA, 0u, P0A)                                                   \
        PUSH(fNB, iNB, 0u, P0B)                                                   \
        __syncthreads();                                                          \
        if (cornerTile) {                                                         \
            if (tid == 0) {                                                       \
                int gy = (ty == 0) ? 0 : 1023;                                    \
                int gx = (tx == 0) ? 0 : 1023;                                    \
                int p = (9 + (gy - by0)) * PRW + 12 + (gx - bx0);                 \
                if (((MC)[(gy << 7) + (gx >> 3)] >> (gx & 7)) & 1u) v[p] = 0.0f;  \
            }                                                                     \
            __syncthreads();                                                      \
        }                                                                         \
        const int n = qn;                                                         \
        if (n <= QCAP) wl_jacobi(v, w, q, n, chgf, pendf, tid);                   \
        else           dense_sweep(v, w, w32, chgf, tid);                         \
        _Pragma("unroll")                                                         \
        for (int k = 0; k < 2; ++k) {                                             \
            int r  = r0 + k * 32;                                                 \
            int p0 = (9 + r) * PRW + 12 + cg0 * 4;                                \
            unsigned int cw = w32[p0 >> 2];                                       \
            float4 vv = *reinterpret_cast<const float4*>(&v[p0]);                 \
            float4 xx = (k == 0) ? (XX0) : (XX1);                                 \
            float4 o;                                                             \
            o.x = (cw & 0x00000080u) ? vv.x : xx.x;                               \
            o.y = (cw & 0x00008000u) ? vv.y : xx.y;                               \
            o.z = (cw & 0x00800000u) ? vv.z : xx.z;                               \
            o.w = (cw & 0x80000000u) ? vv.w : xx.w;                               \
            *reinterpret_cast<float4*>((OC) + (by0 + r) * 1024 + bx0 + cg0 * 4) = o; \
        }                                                                         \
    }

#define PUSH(m_, iv_, pd_, gp_) { unsigned int m = (m_); while (m) {              \
        int b = __builtin_ctz(m); m &= m - 1;                                     \
        unsigned int e = (unsigned int)((gp_) + b) | ((((iv_) >> b) & 1u) << 14)  \
                         | ((((pd_) >> b) & 1u) << 15);                           \
        if (idx < QCAP) q[idx] = (unsigned short)e; ++idx; } }

    // ================= tile A =================
    {
        ENCODE_TILE(mb0A, mb1A, ambA, bmbA, xx0A, xx1A, axxA, bxxA)
        // prefetch tile B (x + masks); flies under A's worklist/Jacobi/epilogue
        xx0B = *reinterpret_cast<const float4*>(xcB + gi0);
        xx1B = *reinterpret_cast<const float4*>(xcB + gi1);
        if (ain) axxB = *reinterpret_cast<const float4*>(xcB + giA);
        if (bin) bxxB = *reinterpret_cast<const float4*>(xcB + giB);
        mb0B = mcB[mi0]; mb1B = mcB[mi1];
        if (ain) ambB = mcB[miA];
        if (bin) bmbB = mcB[miB];
        BUILD_RUN_STORE(mcA, ocA, xx0A, xx1A)
    }

    // ---- inter-tile reset (double barrier: reads done, then resets visible) ----
    __syncthreads();
    if (tid < 8) { chgf[tid] = 0; pendf[tid] = 0; }
    if (tid == 0) qn = 0;
    __syncthreads();

    // ================= tile B =================
    {
        ENCODE_TILE(mb0B, mb1B, ambB, bmbB, xx0B, xx1B, axxB, bxxB)
        BUILD_RUN_STORE(mcB, ocB, xx0B, xx1B)
    }
#undef PUSH
#undef BUILD_RUN_STORE
#undef ENCODE_TILE
}

extern "C" void kernel_launch(void* const* d_in, const int* in_sizes, int n_in,
                              void* d_out, int out_size, void* d_ws, size_t ws_size,
                              hipStream_t stream) {
    (void)in_sizes; (void)n_in; (void)out_size; (void)ws_size;
    const float* x      = (const float*)d_in[0];
    const float* hole_u = (const float*)d_in[1];
    float* out = (float*)d_out;
    unsigned char* u_small  = (unsigned char*)d_ws;           // 256 KiB
    unsigned char* d_small  = u_small + 262144;               // 256 KiB
    unsigned char* inv_mask = d_small + 262144;               // 2 MiB

    k_mask<<<8192, 256, 0, stream>>>(hole_u, inv_mask);       // 2M threads, 8 px each
    k_us  <<<256, 256, 0, stream>>>(inv_mask, u_small);
    k_dil <<<1024, 256, 0, stream>>>(u_small, d_small);
    dim3 grid(16, 16, 8);   // tiles_x, tiles_y, channel pairs (c, c+8)
    k_fill<<<grid, 512, 0, stream>>>(x, inv_mask, d_small, out);
}

// Round 16
// 56.702 us; speedup vs baseline: 1.2294x; 1.2294x over previous
//
#include <hip/hip_runtime.h>

#define HOLE_P 0.05f
#define TW 64
#define TH 64
#define HALO 8
#define PRW 88         // padded row: 3 pad + guard + 80 content + guard + 3 pad
#define PRH 82         // guard + 80 content rows + guard
#define PLN 7216       // PRW*PRH
#define PWORDS 1804
#define QCAP 1536      // worklist capacity (expected ~440, ~27 sigma margin)

// Kernel 1: pack invalid = (hole_u < p) into bitmask, 8 px per byte, flat [c][y][x/8]
__global__ void k_mask(const float* __restrict__ hole_u, unsigned char* __restrict__ inv_mask) {
    int t = blockIdx.x * blockDim.x + threadIdx.x;    // 0 .. 2M-1
    const float* base = hole_u + (size_t)t * 8;
    float4 a = *reinterpret_cast<const float4*>(base);
    float4 b = *reinterpret_cast<const float4*>(base + 4);
    unsigned int m = (a.x < HOLE_P ? 1u : 0u)  | (a.y < HOLE_P ? 2u : 0u)  |
                     (a.z < HOLE_P ? 4u : 0u)  | (a.w < HOLE_P ? 8u : 0u)  |
                     (b.x < HOLE_P ? 16u : 0u) | (b.y < HOLE_P ? 32u : 0u) |
                     (b.z < HOLE_P ? 64u : 0u) | (b.w < HOLE_P ? 128u : 0u);
    inv_mask[t] = (unsigned char)m;
}

// Kernel 2: u_small[i][j] = OR over channels of invalid[c][2i][2j]
__global__ void k_us(const unsigned char* __restrict__ inv_mask, unsigned char* __restrict__ u_small) {
    int t = blockIdx.x * blockDim.x + threadIdx.x;    // 0 .. 65535
    int i  = t >> 7;
    int jb = t & 127;
    const unsigned char* p = inv_mask + (i << 8) + jb;
    unsigned int b = 0;
#pragma unroll
    for (int c = 0; c < 16; ++c) b |= p[c * 131072];
    unsigned int o = (b & 1u) | (((b >> 2) & 1u) << 8) | (((b >> 4) & 1u) << 16) | (((b >> 6) & 1u) << 24);
    *reinterpret_cast<unsigned int*>(u_small + i * 512 + jb * 4) = o;
}

// Kernel 3: d_small = cross-dilate(u_small), zero pad
__global__ void k_dil(const unsigned char* __restrict__ u_small, unsigned char* __restrict__ d_small) {
    int g = blockIdx.x * blockDim.x + threadIdx.x;
    int i = g >> 9, j = g & 511;
    unsigned char d = u_small[g];
    if (i > 0)   d |= u_small[g - 512];
    if (i < 511) d |= u_small[g + 512];
    if (j > 0)   d |= u_small[g - 1];
    if (j < 511) d |= u_small[g + 1];
    d_small[g] = d;
}

// Halo group index h (0..575) -> (row 0..79, col-group 0..19) of 80x80 content.
__device__ __forceinline__ void halo_map(int h, int& ly, int& lxg) {
    if (h < 160)      { ly = h / 20;                lxg = h - (h / 20) * 20; }
    else if (h < 320) { int t2 = h - 160; ly = 72 + t2 / 20; lxg = t2 - (t2 / 20) * 20; }
    else              { int t2 = h - 320; ly = 8 + (t2 >> 2); int q = t2 & 3; lxg = q < 2 ? q : q + 16; }
}

// State-word encode from src/invalid nibbles (bit i -> byte i).
__device__ __forceinline__ unsigned int enc_w(unsigned int src, unsigned int nib) {
    return ((src * 0x204081u) & 0x01010101u) | (((nib * 0x204081u) & 0x01010101u) << 7);
}

// Reciprocal of cnt in {1,2,3,4} via selects.
__device__ __forceinline__ float rcp_cnt(int cn) {
    float lo = (cn == 1) ? 1.0f : 0.5f;
    float hi = (cn == 3) ? (1.0f / 3.0f) : 0.25f;
    return (cn <= 2) ? lo : hi;
}

// Worklist Jacobi: 1 px/lane; states monotone; pending/stationary exits.
__device__ __forceinline__ void wl_jacobi(
    float* v, unsigned char* w, const unsigned short* q, int n,
    int* chgf, int* pendf, int tid)
{
    for (int it = 0; it < 8; ++it) {
        int chg = 0, pend = 0;
        unsigned int thr = (unsigned int)it;
        for (int i = tid; i < n; i += 512) {
            unsigned int e = q[i];
            int p = e & 0x1fffu;
            if (w[p] & 0x7fu) continue;            // already filled
            unsigned int qu = w[p - PRW] & 0x7fu;
            unsigned int qd = w[p + PRW] & 0x7fu;
            unsigned int ql = w[p - 1]   & 0x7fu;
            unsigned int qr = w[p + 1]   & 0x7fu;
            bool su = (qu - 1u) <= thr, sd = (qd - 1u) <= thr;
            bool sl = (ql - 1u) <= thr, sr = (qr - 1u) <= thr;
            float s = (su ? v[p - PRW] : 0.0f) + (sd ? v[p + PRW] : 0.0f)
                    + (sl ? v[p - 1]   : 0.0f) + (sr ? v[p + 1]   : 0.0f);
            int cn = (int)su + (int)sd + (int)sl + (int)sr;
            if (cn > 0) {
                v[p] = s * rcp_cnt(cn);            // reads gated by old states
                w[p] = (unsigned char)((((e >> 14) & 1u) << 7) | (unsigned int)(it + 2));
                chg = 1;
            } else {
                pend |= (int)((e >> 15) & 1u);
            }
        }
        if (chg)  chgf[it] = 1;                    // benign all-write-1 races
        if (pend) pendf[it] = 1;
        __syncthreads();
        if (chgf[it] == 0 || pendf[it] == 0) break;
    }
}

// Dense fallback (worklist overflow, ~never): full sweeps, exact per-byte test.
__device__ __forceinline__ void dense_sweep(
    float* v, unsigned char* w, unsigned int* w32, int* chgf, int tid)
{
    for (int it = 0; it < 8; ++it) {
        int chg = 0;
        unsigned int thr = (unsigned int)it;
        for (int wp = tid; wp < PWORDS; wp += 512) {
            unsigned int cw = w32[wp];
            unsigned int st = cw & 0x7f7f7f7fu;
            if ((((st - 0x01010101u) & ~st) & 0x80808080u) == 0u) continue;
            int p0 = wp * 4;
#pragma unroll
            for (int b = 0; b < 4; ++b) {
                if (((st >> (8 * b)) & 0x7fu) != 0u) continue;
                int p = p0 + b;
                unsigned int qu = w[p - PRW] & 0x7fu, qd = w[p + PRW] & 0x7fu;
                unsigned int ql = w[p - 1] & 0x7fu,   qr = w[p + 1] & 0x7fu;
                bool su = (qu - 1u) <= thr, sd = (qd - 1u) <= thr;
                bool sl = (ql - 1u) <= thr, sr = (qr - 1u) <= thr;
                float s = (su ? v[p - PRW] : 0.0f) + (sd ? v[p + PRW] : 0.0f)
                        + (sl ? v[p - 1]   : 0.0f) + (sr ? v[p + 1]   : 0.0f);
                int cn = (int)su + (int)sd + (int)sl + (int)sr;
                if (cn > 0) {
                    v[p] = s * rcp_cnt(cn);
                    w[p] = (unsigned char)(((cw >> (8 * b)) & 0x80u) | (unsigned int)(it + 2));
                    chg = 1;
                }
            }
        }
        if (chg) chgf[it] = 1;
        __syncthreads();
        if (chgf[it] == 0) break;
    }
}

// Kernel 4: 2-tile software pipeline (channels c and c+8 at same (tx,ty)).
// Tile B's x/mask loads are issued right after tile A's encode and fly under
// A's worklist+Jacobi+epilogue. Grid 2048 = 4 blocks/CU + one replacement
// round. R15 ERRATUM: __launch_bounds__(512,8) capped VGPRs (allocator hit 32)
// and SPILLED the prefetch to scratch (+53 MB WRITE / +26 MB FETCH). (512,4)
// lets the prefetch live in ~56-64 VGPRs; <=64 VGPR still allows 8 waves/SIMD,
// LDS (39.4 KB) remains the 4-block/CU limiter.
__global__ __launch_bounds__(512, 4) void k_fill(
    const float* __restrict__ x, const unsigned char* __restrict__ inv_mask,
    const unsigned char* __restrict__ d_small, float* __restrict__ out)
{
    __shared__ __align__(16) float v[PLN];
    __shared__ unsigned int w32[PWORDS];
    __shared__ unsigned short q[QCAP];
    __shared__ int qn;
    __shared__ int chgf[8], pendf[8];
    unsigned char* w = (unsigned char*)w32;

    const int tid = threadIdx.x;
    const int lane = tid & 63;
    const int tx = blockIdx.x, ty = blockIdx.y;
    const int cA = blockIdx.z;                       // 0..7; tile B = cA+8
    const int by0 = ty * TH, bx0 = tx * TW;
    const bool cornerTile = ((tx == 0) | (tx == 15)) & ((ty == 0) | (ty == 15));

    const float* xcA = x + cA * 1048576;
    const float* xcB = xcA + 8 * 1048576;
    const unsigned char* mcA = inv_mask + cA * 131072;
    const unsigned char* mcB = mcA + 8 * 131072;
    float* ocA = out + cA * 1048576;
    float* ocB = ocA + 8 * 1048576;

    // ---- tile-invariant geometry ----
    const int r0 = tid >> 4, cg0 = tid & 15;
    const int gy0 = by0 + r0, gx0 = bx0 + cg0 * 4, gy1 = gy0 + 32;
    const int gi0 = gy0 * 1024 + gx0, gi1 = gy1 * 1024 + gx0;
    const int mi0 = (gy0 << 7) + (gx0 >> 3), mi1 = (gy1 << 7) + (gx0 >> 3);
    int aly, alxg, bly, blxg;
    halo_map(tid, aly, alxg);
    const bool hasB = (tid < 64);
    halo_map(hasB ? tid + 512 : 0, bly, blxg);
    const int agy = by0 - HALO + aly, agx0 = bx0 - HALO + alxg * 4;
    const int bgy = by0 - HALO + bly, bgx0 = bx0 - HALO + blxg * 4;
    const bool ain = ((unsigned)agy < 1024u) & ((unsigned)agx0 < 1024u);
    const bool bin = hasB & ((unsigned)bgy < 1024u) & ((unsigned)bgx0 < 1024u);
    const int giA = agy * 1024 + agx0, miA = (agy << 7) + (agx0 >> 3), diA = ((agy >> 1) << 9) + (agx0 >> 1);
    const int giB = bgy * 1024 + bgx0, miB = (bgy << 7) + (bgx0 >> 3), diB = ((bgy >> 1) << 9) + (bgx0 >> 1);
    const int P0i0 = (9 + r0) * PRW + 12 + cg0 * 4;
    const int P0i1 = P0i0 + 32 * PRW;
    const int P0A = (aly + 1) * PRW + 4 + alxg * 4;
    const int P0B = (bly + 1) * PRW + 4 + blxg * 4;

    // ---- tile A loads (up front, max MLP) ----
    float4 z4 = make_float4(0.f, 0.f, 0.f, 0.f);
    float4 xx0A = *reinterpret_cast<const float4*>(xcA + gi0);
    float4 xx1A = *reinterpret_cast<const float4*>(xcA + gi1);
    float4 axxA = z4, bxxA = z4;
    if (ain) axxA = *reinterpret_cast<const float4*>(xcA + giA);
    if (bin) bxxA = *reinterpret_cast<const float4*>(xcA + giB);
    unsigned int mb0A = mcA[mi0], mb1A = mcA[mi1];
    unsigned int ambA = ain ? mcA[miA] : 0u;
    unsigned int bmbA = bin ? mcA[miB] : 0u;
    // d_small: channel-independent -> load once, reuse for both tiles
    unsigned int ds0 = *reinterpret_cast<const unsigned short*>(d_small + ((gy0 >> 1) << 9) + (gx0 >> 1));
    unsigned int ds1 = *reinterpret_cast<const unsigned short*>(d_small + ((gy1 >> 1) << 9) + (gx0 >> 1));
    unsigned int dsa = ain ? *reinterpret_cast<const unsigned short*>(d_small + diA) : 0u;
    unsigned int dsb = bin ? *reinterpret_cast<const unsigned short*>(d_small + diB) : 0u;
    const unsigned int db0 = ((ds0 & 0xffu) ? 0x3u : 0u) | ((ds0 & 0xff00u) ? 0xcu : 0u);
    const unsigned int db1 = ((ds1 & 0xffu) ? 0x3u : 0u) | ((ds1 & 0xff00u) ? 0xcu : 0u);
    const unsigned int dbA = ((dsa & 0xffu) ? 0x3u : 0u) | ((dsa & 0xff00u) ? 0xcu : 0u);
    const unsigned int dbB = ((dsb & 0xffu) ? 0x3u : 0u) | ((dsb & 0xff00u) ? 0xcu : 0u);
    const unsigned int crn0 = (cornerTile && ((gy0 == 0) | (gy0 == 1023)))
                              ? ((gx0 == 0 ? 1u : 0u) | (gx0 == 1020 ? 8u : 0u)) : 0u;
    const unsigned int crn1 = (cornerTile && ((gy1 == 0) | (gy1 == 1023)))
                              ? ((gx0 == 0 ? 1u : 0u) | (gx0 == 1020 ? 8u : 0u)) : 0u;

    // ---- flags + guard ring init ----
    if (tid < 8) { chgf[tid] = 0; pendf[tid] = 0; }
    if (tid == 0) qn = 0;
    if (tid < 204) {
        int wi;
        if (tid < 22)      wi = tid;
        else if (tid < 44) wi = 81 * 22 + (tid - 22);
        else { int r = ((tid - 44) >> 1) + 1; wi = r * 22 + (((tid - 44) & 1) ? 21 : 0); }
        w32[wi] = 0x7f7f7f7fu;
    }
    __syncthreads();

    float4 xx0B, xx1B, axxB = z4, bxxB = z4;
    unsigned int mb0B, mb1B, ambB = 0u, bmbB = 0u;

#define ENCODE_TILE(MB0, MB1, AMB, BMB, XX0, XX1, AXX, BXX)                       \
    unsigned int fN0, fN1, fNA = 0, fNB = 0;                                      \
    unsigned int iN0, iN1, iNA = 0, iNB = 0;                                      \
    {                                                                             \
        unsigned int nib = ((MB0) >> (gx0 & 7)) & 0xfu;                           \
        unsigned int src = (db0 & ~nib & 0xfu) | crn0;                            \
        *reinterpret_cast<float4*>(&v[P0i0]) = (XX0);                             \
        w32[P0i0 >> 2] = enc_w(src, nib);                                         \
        fN0 = ~src & 0xfu; iN0 = nib;                                             \
    }                                                                             \
    {                                                                             \
        unsigned int nib = ((MB1) >> (gx0 & 7)) & 0xfu;                           \
        unsigned int src = (db1 & ~nib & 0xfu) | crn1;                            \
        *reinterpret_cast<float4*>(&v[P0i1]) = (XX1);                             \
        w32[P0i1 >> 2] = enc_w(src, nib);                                         \
        fN1 = ~src & 0xfu; iN1 = nib;                                             \
    }                                                                             \
    {                                                                             \
        unsigned int ww = 0x7f7f7f7fu;                                            \
        if (ain) {                                                                \
            unsigned int nib = ((AMB) >> (agx0 & 7)) & 0xfu;                      \
            unsigned int src = dbA & ~nib & 0xfu;                                 \
            ww = enc_w(src, nib);                                                 \
            fNA = ~src & 0xfu; iNA = nib;                                         \
        }                                                                         \
        *reinterpret_cast<float4*>(&v[P0A]) = (AXX);                              \
        w32[P0A >> 2] = ww;                                                       \
    }                                                                             \
    if (hasB) {                                                                   \
        unsigned int ww = 0x7f7f7f7fu;                                            \
        if (bin) {                                                                \
            unsigned int nib = ((BMB) >> (bgx0 & 7)) & 0xfu;                      \
            unsigned int src = dbB & ~nib & 0xfu;                                 \
            ww = enc_w(src, nib);                                                 \
            fNB = ~src & 0xfu; iNB = nib;                                         \
        }                                                                         \
        *reinterpret_cast<float4*>(&v[P0B]) = (BXX);                              \
        w32[P0B >> 2] = ww;                                                       \
    }

#define BUILD_RUN_STORE(MC, OC, XX0, XX1)                                         \
    {                                                                             \
        int cnt = __popc(fN0) + __popc(fN1) + __popc(fNA) + __popc(fNB);          \
        int xsum = cnt;                                                           \
        _Pragma("unroll")                                                         \
        for (int d = 1; d < 64; d <<= 1) {                                        \
            int y = __shfl_up(xsum, d, 64);                                       \
            if (lane >= d) xsum += y;                                             \
        }                                                                         \
        int base = 0;                                                             \
        if (lane == 63) base = atomicAdd(&qn, xsum);                              \
        base = __shfl(base, 63, 64);                                              \
        int idx = base + (xsum - cnt);                                            \
        PUSH(fN0, iN0, fN0 & iN0, P0i0)                                           \
        PUSH(fN1, iN1, fN1 & iN1, P0i1)                                           \
        PUSH(fNA, iNA, 0u, P0A)                                                   \
        PUSH(fNB, iNB, 0u, P0B)                                                   \
        __syncthreads();                                                          \
        if (cornerTile) {                                                         \
            if (tid == 0) {                                                       \
                int gy = (ty == 0) ? 0 : 1023;                                    \
                int gx = (tx == 0) ? 0 : 1023;                                    \
                int p = (9 + (gy - by0)) * PRW + 12 + (gx - bx0);                 \
                if (((MC)[(gy << 7) + (gx >> 3)] >> (gx & 7)) & 1u) v[p] = 0.0f;  \
            }                                                                     \
            __syncthreads();                                                      \
        }                                                                         \
        const int n = qn;                                                         \
        if (n <= QCAP) wl_jacobi(v, w, q, n, chgf, pendf, tid);                   \
        else           dense_sweep(v, w, w32, chgf, tid);                         \
        _Pragma("unroll")                                                         \
        for (int k = 0; k < 2; ++k) {                                             \
            int r  = r0 + k * 32;                                                 \
            int p0 = (9 + r) * PRW + 12 + cg0 * 4;                                \
            unsigned int cw = w32[p0 >> 2];                                       \
            float4 vv = *reinterpret_cast<const float4*>(&v[p0]);                 \
            float4 xx = (k == 0) ? (XX0) : (XX1);                                 \
            float4 o;                                                             \
            o.x = (cw & 0x00000080u) ? vv.x : xx.x;                               \
            o.y = (cw & 0x00008000u) ? vv.y : xx.y;                               \
            o.z = (cw & 0x00800000u) ? vv.z : xx.z;                               \
            o.w = (cw & 0x80000000u) ? vv.w : xx.w;                               \
            *reinterpret_cast<float4*>((OC) + (by0 + r) * 1024 + bx0 + cg0 * 4) = o; \
        }                                                                         \
    }

#define PUSH(m_, iv_, pd_, gp_) { unsigned int m = (m_); while (m) {              \
        int b = __builtin_ctz(m); m &= m - 1;                                     \
        unsigned int e = (unsigned int)((gp_) + b) | ((((iv_) >> b) & 1u) << 14)  \
                         | ((((pd_) >> b) & 1u) << 15);                           \
        if (idx < QCAP) q[idx] = (unsigned short)e; ++idx; } }

    // ================= tile A =================
    {
        ENCODE_TILE(mb0A, mb1A, ambA, bmbA, xx0A, xx1A, axxA, bxxA)
        // prefetch tile B (x + masks); flies under A's worklist/Jacobi/epilogue
        xx0B = *reinterpret_cast<const float4*>(xcB + gi0);
        xx1B = *reinterpret_cast<const float4*>(xcB + gi1);
        if (ain) axxB = *reinterpret_cast<const float4*>(xcB + giA);
        if (bin) bxxB = *reinterpret_cast<const float4*>(xcB + giB);
        mb0B = mcB[mi0]; mb1B = mcB[mi1];
        if (ain) ambB = mcB[miA];
        if (bin) bmbB = mcB[miB];
        BUILD_RUN_STORE(mcA, ocA, xx0A, xx1A)
    }

    // ---- inter-tile reset (double barrier: reads done, then resets visible) ----
    __syncthreads();
    if (tid < 8) { chgf[tid] = 0; pendf[tid] = 0; }
    if (tid == 0) qn = 0;
    __syncthreads();

    // ================= tile B =================
    {
        ENCODE_TILE(mb0B, mb1B, ambB, bmbB, xx0B, xx1B, axxB, bxxB)
        BUILD_RUN_STORE(mcB, ocB, xx0B, xx1B)
    }
#undef PUSH
#undef BUILD_RUN_STORE
#undef ENCODE_TILE
}

extern "C" void kernel_launch(void* const* d_in, const int* in_sizes, int n_in,
                              void* d_out, int out_size, void* d_ws, size_t ws_size,
                              hipStream_t stream) {
    (void)in_sizes; (void)n_in; (void)out_size; (void)ws_size;
    const float* x      = (const float*)d_in[0];
    const float* hole_u = (const float*)d_in[1];
    float* out = (float*)d_out;
    unsigned char* u_small  = (unsigned char*)d_ws;           // 256 KiB
    unsigned char* d_small  = u_small + 262144;               // 256 KiB
    unsigned char* inv_mask = d_small + 262144;               // 2 MiB

    k_mask<<<8192, 256, 0, stream>>>(hole_u, inv_mask);       // 2M threads, 8 px each
    k_us  <<<256, 256, 0, stream>>>(inv_mask, u_small);
    k_dil <<<1024, 256, 0, stream>>>(u_small, d_small);
    dim3 grid(16, 16, 8);   // tiles_x, tiles_y, channel pairs (c, c+8)
    k_fill<<<grid, 512, 0, stream>>>(x, inv_mask, d_small, out);
}

// Round 18
// 56.080 us; speedup vs baseline: 1.2430x; 1.0111x over previous
//
#include <hip/hip_runtime.h>

#define HOLE_P 0.05f
#define TW 64          // tile width
#define TH 64          // tile height
#define HALO 8
#define PRW 88         // padded row: 3 pad + guard + 80 content + guard + 3 pad
#define PRH 82         // guard + 80 content rows + guard
#define PLN 7216       // PRW*PRH
#define PWORDS 1804
#define QCAP 1536      // worklist capacity (expected ~440, ~27 sigma margin)

typedef float f32x4 __attribute__((ext_vector_type(4)));   // NT builtins need native vectors

// Kernel 1: pack invalid = (hole_u < p) into bitmask, 8 px per byte, flat [c][y][x/8]
// hole_u is streamed exactly once -> non-temporal loads (don't pollute L2).
__global__ void k_mask(const float* __restrict__ hole_u, unsigned char* __restrict__ inv_mask) {
    int t = blockIdx.x * blockDim.x + threadIdx.x;    // 0 .. 2M-1
    const f32x4* base = reinterpret_cast<const f32x4*>(hole_u + (size_t)t * 8);
    f32x4 a = __builtin_nontemporal_load(base);
    f32x4 b = __builtin_nontemporal_load(base + 1);
    unsigned int m = (a.x < HOLE_P ? 1u : 0u)  | (a.y < HOLE_P ? 2u : 0u)  |
                     (a.z < HOLE_P ? 4u : 0u)  | (a.w < HOLE_P ? 8u : 0u)  |
                     (b.x < HOLE_P ? 16u : 0u) | (b.y < HOLE_P ? 32u : 0u) |
                     (b.z < HOLE_P ? 64u : 0u) | (b.w < HOLE_P ? 128u : 0u);
    inv_mask[t] = (unsigned char)m;
}

// Kernel 2: u_small[i][j] = OR over channels of invalid[c][2i][2j]
__global__ void k_us(const unsigned char* __restrict__ inv_mask, unsigned char* __restrict__ u_small) {
    int t = blockIdx.x * blockDim.x + threadIdx.x;    // 0 .. 65535
    int i  = t >> 7;
    int jb = t & 127;
    const unsigned char* p = inv_mask + (i << 8) + jb;
    unsigned int b = 0;
#pragma unroll
    for (int c = 0; c < 16; ++c) b |= p[c * 131072];
    unsigned int o = (b & 1u) | (((b >> 2) & 1u) << 8) | (((b >> 4) & 1u) << 16) | (((b >> 6) & 1u) << 24);
    *reinterpret_cast<unsigned int*>(u_small + i * 512 + jb * 4) = o;
}

// Kernel 3: d_small = cross-dilate(u_small), zero pad
__global__ void k_dil(const unsigned char* __restrict__ u_small, unsigned char* __restrict__ d_small) {
    int g = blockIdx.x * blockDim.x + threadIdx.x;
    int i = g >> 9, j = g & 511;
    unsigned char d = u_small[g];
    if (i > 0)   d |= u_small[g - 512];
    if (i < 511) d |= u_small[g + 512];
    if (j > 0)   d |= u_small[g - 1];
    if (j < 511) d |= u_small[g + 1];
    d_small[g] = d;
}

// Halo group index h (0..575) -> (row 0..79, col-group 0..19) of 80x80 content.
__device__ __forceinline__ void halo_map(int h, int& ly, int& lxg) {
    if (h < 160)      { ly = h / 20;                lxg = h - (h / 20) * 20; }
    else if (h < 320) { int t2 = h - 160; ly = 72 + t2 / 20; lxg = t2 - (t2 / 20) * 20; }
    else              { int t2 = h - 320; ly = 8 + (t2 >> 2); int q = t2 & 3; lxg = q < 2 ? q : q + 16; }
}

// State-word encode from src/invalid nibbles (bit i -> byte i).
__device__ __forceinline__ unsigned int enc_w(unsigned int src, unsigned int nib) {
    return ((src * 0x204081u) & 0x01010101u) | (((nib * 0x204081u) & 0x01010101u) << 7);
}

// Reciprocal of cnt in {1,2,3,4} via selects (no div, no array->scratch).
__device__ __forceinline__ float rcp_cnt(int cn) {
    float lo = (cn == 1) ? 1.0f : 0.5f;
    float hi = (cn == 3) ? (1.0f / 3.0f) : 0.25f;
    return (cn <= 2) ? lo : hi;
}

// Kernel 4: per-channel 64x64 tiles, halo 8, guard-ring padded LDS region.
// w byte: bit7 = invalid; low7: 0 = fillable, 1 = source, it+2 = filled at it,
// 0x7f = guard/out-of-image. v = x EVERYWHERE at init (v[p] only read when p
// is a contributor; fills overwrite first). 4 forced-source invalid corners
// patched to v=0 under barrier. Fillable pixels (~440/tile) -> wave-compacted
// worklist, 1 px/lane/iter. Exits: nothing filled, or no pending interior-
// invalid. Epilogue: blended NON-TEMPORAL store out = bit7 ? v : x_reg (out is
// never re-read; keep L2 for x-halo reuse). WRITE stays at the 65.5 MB ideal.
__global__ __launch_bounds__(512, 4) void k_fill(
    const float* __restrict__ x, const unsigned char* __restrict__ inv_mask,
    const unsigned char* __restrict__ d_small, float* __restrict__ out)
{
    __shared__ __align__(16) float v[PLN];
    __shared__ unsigned int w32[PWORDS];
    __shared__ unsigned short q[QCAP];
    __shared__ int qn;
    __shared__ int chgf[8], pendf[8];
    unsigned char* w = (unsigned char*)w32;

    const int tid = threadIdx.x;
    const int c   = blockIdx.z;
    const int by0 = blockIdx.y * TH;
    const int bx0 = blockIdx.x * TW;
    const float* xc = x + c * 1048576;
    const unsigned char* mc = inv_mask + c * 131072;
    float* oc = out + c * 1048576;
    const bool cornerTile = ((blockIdx.x == 0) | (blockIdx.x == 15)) &
                            ((blockIdx.y == 0) | (blockIdx.y == 15));

    if (tid < 8) { chgf[tid] = 0; pendf[tid] = 0; }
    if (tid == 0) qn = 0;
    if (tid < 204) {                      // guard ring + pads = 0x7f sentinel
        int wi;
        if (tid < 22)      wi = tid;                         // top row (row 0)
        else if (tid < 44) wi = 81 * 22 + (tid - 22);        // bottom row (row 81)
        else {                                               // rows 1..80, left/right word
            int r = ((tid - 44) >> 1) + 1;
            wi = r * 22 + (((tid - 44) & 1) ? 21 : 0);
        }
        w32[wi] = 0x7f7f7f7fu;
    }
    __syncthreads();                      // qn=0 visible before atomics

    // ---- global loads (max MLP: all issued up front) ----
    int r0  = tid >> 4, cg0 = tid & 15;
    int gy0 = by0 + r0,      gx0 = bx0 + cg0 * 4;
    int gy1 = by0 + r0 + 32;
    float4 xx0 = *reinterpret_cast<const float4*>(xc + gy0 * 1024 + gx0);
    float4 xx1 = *reinterpret_cast<const float4*>(xc + gy1 * 1024 + gx0);
    unsigned int mb0 = mc[(gy0 << 7) + (gx0 >> 3)];
    unsigned int mb1 = mc[(gy1 << 7) + (gx0 >> 3)];
    unsigned short dsA = *reinterpret_cast<const unsigned short*>(d_small + ((gy0 >> 1) << 9) + (gx0 >> 1));
    unsigned short dsB = *reinterpret_cast<const unsigned short*>(d_small + ((gy1 >> 1) << 9) + (gx0 >> 1));

    // halo: 576 groups = hA (all 512 threads) + hB (tid<64 -> h = tid+512)
    int aly, alxg, bly, blxg;
    halo_map(tid, aly, alxg);
    const bool hasB = (tid < 64);
    halo_map(hasB ? tid + 512 : 0, bly, blxg);
    int agy  = by0 - HALO + aly,  agx0 = bx0 - HALO + alxg * 4;
    int bgy  = by0 - HALO + bly,  bgx0 = bx0 - HALO + blxg * 4;
    bool ain = ((unsigned)agy < 1024u) & ((unsigned)agx0 < 1024u);
    bool bin = hasB & ((unsigned)bgy < 1024u) & ((unsigned)bgx0 < 1024u);
    float4 axx = make_float4(0.f, 0.f, 0.f, 0.f), bxx = axx;
    unsigned int amb = 0, bmb = 0; unsigned short ads = 0, bds = 0;
    if (ain) {
        int gi = agy * 1024 + agx0;
        axx = *reinterpret_cast<const float4*>(xc + gi);
        amb = mc[(agy << 7) + (agx0 >> 3)];
        ads = *reinterpret_cast<const unsigned short*>(d_small + ((agy >> 1) << 9) + (agx0 >> 1));
    }
    if (bin) {
        int gi = bgy * 1024 + bgx0;
        bxx = *reinterpret_cast<const float4*>(xc + gi);
        bmb = mc[(bgy << 7) + (bgx0 >> 3)];
        bds = *reinterpret_cast<const unsigned short*>(d_small + ((bgy >> 1) << 9) + (bgx0 >> 1));
    }

    // ---- encode + LDS writes (v = x unconditionally); collect nibbles ----
    unsigned int fN0, fN1, fNA = 0, fNB = 0;   // fillable nibbles
    unsigned int iN0, iN1, iNA = 0, iNB = 0;   // invalid nibbles
    int P0i0, P0i1, P0A, P0B;
    {
        unsigned int nib = (mb0 >> (gx0 & 7)) & 0xfu;
        unsigned int db = ((dsA & 0xffu) ? 0x3u : 0u) | ((dsA & 0xff00u) ? 0xcu : 0u);
        unsigned int src = db & ~nib & 0xfu;
        if (cornerTile && ((gy0 == 0) | (gy0 == 1023)))
            src |= (gx0 == 0 ? 1u : 0u) | (gx0 == 1020 ? 8u : 0u);
        P0i0 = (9 + r0) * PRW + 12 + cg0 * 4;
        *reinterpret_cast<float4*>(&v[P0i0]) = xx0;
        w32[P0i0 >> 2] = enc_w(src, nib);
        fN0 = ~src & 0xfu; iN0 = nib;
    }
    {
        unsigned int nib = (mb1 >> (gx0 & 7)) & 0xfu;
        unsigned int db = ((dsB & 0xffu) ? 0x3u : 0u) | ((dsB & 0xff00u) ? 0xcu : 0u);
        unsigned int src = db & ~nib & 0xfu;
        if (cornerTile && ((gy1 == 0) | (gy1 == 1023)))
            src |= (gx0 == 0 ? 1u : 0u) | (gx0 == 1020 ? 8u : 0u);
        P0i1 = (9 + r0 + 32) * PRW + 12 + cg0 * 4;
        *reinterpret_cast<float4*>(&v[P0i1]) = xx1;
        w32[P0i1 >> 2] = enc_w(src, nib);
        fN1 = ~src & 0xfu; iN1 = nib;
    }
    {   // halo A (all threads)
        P0A = (aly + 1) * PRW + 4 + alxg * 4;
        unsigned int ww = 0x7f7f7f7fu;
        if (ain) {
            unsigned int nib = (amb >> (agx0 & 7)) & 0xfu;
            unsigned int db = ((ads & 0xffu) ? 0x3u : 0u) | ((ads & 0xff00u) ? 0xcu : 0u);
            unsigned int src = db & ~nib & 0xfu;     // corners never in halo
            ww = enc_w(src, nib);
            fNA = ~src & 0xfu; iNA = nib;
        }
        *reinterpret_cast<float4*>(&v[P0A]) = axx;   // 0 if out-of-image (never read)
        w32[P0A >> 2] = ww;
    }
    P0B = (bly + 1) * PRW + 4 + blxg * 4;
    if (hasB) {   // halo B (tid < 64)
        unsigned int ww = 0x7f7f7f7fu;
        if (bin) {
            unsigned int nib = (bmb >> (bgx0 & 7)) & 0xfu;
            unsigned int db = ((bds & 0xffu) ? 0x3u : 0u) | ((bds & 0xff00u) ? 0xcu : 0u);
            unsigned int src = db & ~nib & 0xfu;
            ww = enc_w(src, nib);
            fNB = ~src & 0xfu; iNB = nib;
        }
        *reinterpret_cast<float4*>(&v[P0B]) = bxx;
        w32[P0B >> 2] = ww;
    }

    // ---- wave-compacted worklist build (prefix-sum + 1 atomic per wave) ----
    int cnt = __popc(fN0) + __popc(fN1) + __popc(fNA) + __popc(fNB);
    int lane = tid & 63;
    int xsum = cnt;
#pragma unroll
    for (int d = 1; d < 64; d <<= 1) {
        int y = __shfl_up(xsum, d, 64);
        if (lane >= d) xsum += y;
    }
    int base = 0;
    if (lane == 63) base = atomicAdd(&qn, xsum);
    base = __shfl(base, 63, 64);
    int idx = base + (xsum - cnt);
#define PUSH(m_, iv_, pd_, gp_) { unsigned int m = (m_); while (m) {            \
        int b = __builtin_ctz(m); m &= m - 1;                                   \
        unsigned int e = (unsigned int)((gp_) + b) | ((((iv_) >> b) & 1u) << 14)\
                         | ((((pd_) >> b) & 1u) << 15);                         \
        if (idx < QCAP) q[idx] = (unsigned short)e; ++idx; } }
    PUSH(fN0, iN0, fN0 & iN0, P0i0)        // interior: pend = fillable & invalid
    PUSH(fN1, iN1, fN1 & iN1, P0i1)
    PUSH(fNA, iNA, 0u, P0A)                // halo: never pend-relevant
    PUSH(fNB, iNB, 0u, P0B)
#undef PUSH
    __syncthreads();

    // ---- corner patch: forced-source invalid corner must have v=0 (ref fixup) ----
    if (cornerTile) {
        if (tid == 0) {
            int gy = (blockIdx.y == 0) ? 0 : 1023;
            int gx = (blockIdx.x == 0) ? 0 : 1023;
            int p = (9 + (gy - by0)) * PRW + 12 + (gx - bx0);
            if ((mc[(gy << 7) + (gx >> 3)] >> (gx & 7)) & 1u) v[p] = 0.0f;
        }
        __syncthreads();
    }

    const int n = qn;
    if (n <= QCAP) {
        // ---- worklist Jacobi: 1 px/lane, packed; skip filled via state byte ----
        for (int it = 0; it < 8; ++it) {
            int chg = 0, pend = 0;
            unsigned int thr = (unsigned int)it;
            for (int i = tid; i < n; i += 512) {
                unsigned int e = q[i];
                int p = e & 0x1fffu;
                if (w[p] & 0x7fu) continue;            // already filled
                unsigned int qu = w[p - PRW] & 0x7fu;
                unsigned int qd = w[p + PRW] & 0x7fu;
                unsigned int ql = w[p - 1]   & 0x7fu;
                unsigned int qr = w[p + 1]   & 0x7fu;
                bool su = (qu - 1u) <= thr, sd = (qd - 1u) <= thr;
                bool sl = (ql - 1u) <= thr, sr = (qr - 1u) <= thr;
                float s = (su ? v[p - PRW] : 0.0f) + (sd ? v[p + PRW] : 0.0f)
                        + (sl ? v[p - 1]   : 0.0f) + (sr ? v[p + 1]   : 0.0f);
                int cn = (int)su + (int)sd + (int)sl + (int)sr;
                if (cn > 0) {
                    v[p] = s * rcp_cnt(cn);            // reads gated by old states
                    w[p] = (unsigned char)((((e >> 14) & 1u) << 7) | (unsigned int)(it + 2));
                    chg = 1;
                } else {
                    pend |= (int)((e >> 15) & 1u);
                }
            }
            if (chg)  chgf[it] = 1;                    // benign all-write-1 races
            if (pend) pendf[it] = 1;
            __syncthreads();
            if (chgf[it] == 0 || pendf[it] == 0) break;
        }
    } else {
        // ---- overflow fallback (~never): dense sweeps over all words ----
        for (int it = 0; it < 8; ++it) {
            int chg = 0;
            unsigned int thr = (unsigned int)it;
            for (int wp = tid; wp < PWORDS; wp += 512) {
                unsigned int cw = w32[wp];
                unsigned int st = cw & 0x7f7f7f7fu;
                if ((((st - 0x01010101u) & ~st) & 0x80808080u) == 0u) continue;
                int p0 = wp * 4;
#pragma unroll
                for (int b = 0; b < 4; ++b) {
                    if (((st >> (8 * b)) & 0x7fu) != 0u) continue;  // exact per-byte
                    int p = p0 + b;
                    unsigned int qu = w[p - PRW] & 0x7fu, qd = w[p + PRW] & 0x7fu;
                    unsigned int ql = w[p - 1] & 0x7fu,   qr = w[p + 1] & 0x7fu;
                    bool su = (qu - 1u) <= thr, sd = (qd - 1u) <= thr;
                    bool sl = (ql - 1u) <= thr, sr = (qr - 1u) <= thr;
                    float s = (su ? v[p - PRW] : 0.0f) + (sd ? v[p + PRW] : 0.0f)
                            + (sl ? v[p - 1]   : 0.0f) + (sr ? v[p + 1]   : 0.0f);
                    int cn = (int)su + (int)sd + (int)sl + (int)sr;
                    if (cn > 0) {
                        v[p] = s * rcp_cnt(cn);
                        w[p] = (unsigned char)(((cw >> (8 * b)) & 0x80u) | (unsigned int)(it + 2));
                        chg = 1;
                    }
                }
            }
            if (chg) chgf[it] = 1;
            __syncthreads();
            if (chgf[it] == 0) break;
        }
    }
    // (both Jacobi exits pass through a __syncthreads: w/v stable here)

    // ---- epilogue: one blended coalesced NON-TEMPORAL store of the interior ----
#pragma unroll
    for (int k = 0; k < 2; ++k) {
        int r  = r0 + k * 32;
        int p0 = (9 + r) * PRW + 12 + cg0 * 4;
        unsigned int cw = w32[p0 >> 2];
        float4 vv = *reinterpret_cast<const float4*>(&v[p0]);
        float4 xx = (k == 0) ? xx0 : xx1;
        f32x4 o;
        o.x = (cw & 0x00000080u) ? vv.x : xx.x;
        o.y = (cw & 0x00008000u) ? vv.y : xx.y;
        o.z = (cw & 0x00800000u) ? vv.z : xx.z;
        o.w = (cw & 0x80000000u) ? vv.w : xx.w;
        __builtin_nontemporal_store(o,
            reinterpret_cast<f32x4*>(oc + (by0 + r) * 1024 + bx0 + cg0 * 4));
    }
}

extern "C" void kernel_launch(void* const* d_in, const int* in_sizes, int n_in,
                              void* d_out, int out_size, void* d_ws, size_t ws_size,
                              hipStream_t stream) {
    (void)in_sizes; (void)n_in; (void)out_size; (void)ws_size;
    const float* x      = (const float*)d_in[0];
    const float* hole_u = (const float*)d_in[1];
    float* out = (float*)d_out;
    unsigned char* u_small  = (unsigned char*)d_ws;           // 256 KiB
    unsigned char* d_small  = u_small + 262144;               // 256 KiB
    unsigned char* inv_mask = d_small + 262144;               // 2 MiB

    k_mask<<<8192, 256, 0, stream>>>(hole_u, inv_mask);       // 2M threads, 8 px each
    k_us  <<<256, 256, 0, stream>>>(inv_mask, u_small);
    k_dil <<<1024, 256, 0, stream>>>(u_small, d_small);
    dim3 grid(16, 16, 16);   // tiles_x, tiles_y, channels
    k_fill<<<grid, 512, 0, stream>>>(x, inv_mask, d_small, out);
}

// Round 19
// 53.978 us; speedup vs baseline: 1.2914x; 1.0389x over previous
//
#include <hip/hip_runtime.h>

#define HOLE_P 0.05f
#define TW 64          // tile width
#define TH 64          // tile height
#define HALO 8
#define PRW 88         // padded row: 3 pad + guard + 80 content + guard + 3 pad
#define PRH 82         // guard + 80 content rows + guard
#define PLN 7216       // PRW*PRH
#define PWORDS 1804
#define QCAP 1536      // worklist capacity (expected ~440, ~27 sigma margin)

// Kernel 1: pack invalid = (hole_u < p) into bitmask, 8 px per byte, flat [c][y][x/8]
__global__ void k_mask(const float* __restrict__ hole_u, unsigned char* __restrict__ inv_mask) {
    int t = blockIdx.x * blockDim.x + threadIdx.x;    // 0 .. 2M-1
    const float* base = hole_u + (size_t)t * 8;
    float4 a = *reinterpret_cast<const float4*>(base);
    float4 b = *reinterpret_cast<const float4*>(base + 4);
    unsigned int m = (a.x < HOLE_P ? 1u : 0u)  | (a.y < HOLE_P ? 2u : 0u)  |
                     (a.z < HOLE_P ? 4u : 0u)  | (a.w < HOLE_P ? 8u : 0u)  |
                     (b.x < HOLE_P ? 16u : 0u) | (b.y < HOLE_P ? 32u : 0u) |
                     (b.z < HOLE_P ? 64u : 0u) | (b.w < HOLE_P ? 128u : 0u);
    inv_mask[t] = (unsigned char)m;
}

// Kernel 2: u_small[i][j] = OR over channels of invalid[c][2i][2j]
__global__ void k_us(const unsigned char* __restrict__ inv_mask, unsigned char* __restrict__ u_small) {
    int t = blockIdx.x * blockDim.x + threadIdx.x;    // 0 .. 65535
    int i  = t >> 7;
    int jb = t & 127;
    const unsigned char* p = inv_mask + (i << 8) + jb;
    unsigned int b = 0;
#pragma unroll
    for (int c = 0; c < 16; ++c) b |= p[c * 131072];
    unsigned int o = (b & 1u) | (((b >> 2) & 1u) << 8) | (((b >> 4) & 1u) << 16) | (((b >> 6) & 1u) << 24);
    *reinterpret_cast<unsigned int*>(u_small + i * 512 + jb * 4) = o;
}

// Kernel 3: d_small = cross-dilate(u_small), zero pad
__global__ void k_dil(const unsigned char* __restrict__ u_small, unsigned char* __restrict__ d_small) {
    int g = blockIdx.x * blockDim.x + threadIdx.x;
    int i = g >> 9, j = g & 511;
    unsigned char d = u_small[g];
    if (i > 0)   d |= u_small[g - 512];
    if (i < 511) d |= u_small[g + 512];
    if (j > 0)   d |= u_small[g - 1];
    if (j < 511) d |= u_small[g + 1];
    d_small[g] = d;
}

// Halo group index h (0..575) -> (row 0..79, col-group 0..19) of 80x80 content.
__device__ __forceinline__ void halo_map(int h, int& ly, int& lxg) {
    if (h < 160)      { ly = h / 20;                lxg = h - (h / 20) * 20; }
    else if (h < 320) { int t2 = h - 160; ly = 72 + t2 / 20; lxg = t2 - (t2 / 20) * 20; }
    else              { int t2 = h - 320; ly = 8 + (t2 >> 2); int q = t2 & 3; lxg = q < 2 ? q : q + 16; }
}

// State-word encode from src/invalid nibbles (bit i -> byte i).
__device__ __forceinline__ unsigned int enc_w(unsigned int src, unsigned int nib) {
    return ((src * 0x204081u) & 0x01010101u) | (((nib * 0x204081u) & 0x01010101u) << 7);
}

// Reciprocal of cnt in {1,2,3,4} via selects (no div, no array->scratch).
__device__ __forceinline__ float rcp_cnt(int cn) {
    float lo = (cn == 1) ? 1.0f : 0.5f;
    float hi = (cn == 3) ? (1.0f / 3.0f) : 0.25f;
    return (cn <= 2) ? lo : hi;
}

// Kernel 4: per-channel 64x64 tiles, halo 8, guard-ring padded LDS region.
// w byte: bit7 = invalid; low7: 0 = fillable, 1 = source, it+2 = filled at it,
// 0x7f = guard/out-of-image. v = x EVERYWHERE at init (v[p] only read when p
// is a contributor; fills overwrite first). 4 forced-source invalid corners
// patched to v=0 under barrier. Fillable pixels (~440/tile) -> wave-compacted
// worklist, 1 px/lane/iter. Exits: nothing filled, or no pending interior-
// invalid. Epilogue: blended coalesced store out = bit7 ? v : x_reg (keeps
// WRITE at the 65.5 MB ideal).
__global__ __launch_bounds__(512, 4) void k_fill(
    const float* __restrict__ x, const unsigned char* __restrict__ inv_mask,
    const unsigned char* __restrict__ d_small, float* __restrict__ out)
{
    __shared__ __align__(16) float v[PLN];
    __shared__ unsigned int w32[PWORDS];
    __shared__ unsigned short q[QCAP];
    __shared__ int qn;
    __shared__ int chgf[8], pendf[8];
    unsigned char* w = (unsigned char*)w32;

    const int tid = threadIdx.x;
    const int c   = blockIdx.z;
    const int by0 = blockIdx.y * TH;
    const int bx0 = blockIdx.x * TW;
    const float* xc = x + c * 1048576;
    const unsigned char* mc = inv_mask + c * 131072;
    float* oc = out + c * 1048576;
    const bool cornerTile = ((blockIdx.x == 0) | (blockIdx.x == 15)) &
                            ((blockIdx.y == 0) | (blockIdx.y == 15));

    if (tid < 8) { chgf[tid] = 0; pendf[tid] = 0; }
    if (tid == 0) qn = 0;
    if (tid < 204) {                      // guard ring + pads = 0x7f sentinel
        int wi;
        if (tid < 22)      wi = tid;                         // top row (row 0)
        else if (tid < 44) wi = 81 * 22 + (tid - 22);        // bottom row (row 81)
        else {                                               // rows 1..80, left/right word
            int r = ((tid - 44) >> 1) + 1;
            wi = r * 22 + (((tid - 44) & 1) ? 21 : 0);
        }
        w32[wi] = 0x7f7f7f7fu;
    }
    __syncthreads();                      // qn=0 visible before atomics

    // ---- global loads (max MLP: all issued up front) ----
    int r0  = tid >> 4, cg0 = tid & 15;
    int gy0 = by0 + r0,      gx0 = bx0 + cg0 * 4;
    int gy1 = by0 + r0 + 32;
    float4 xx0 = *reinterpret_cast<const float4*>(xc + gy0 * 1024 + gx0);
    float4 xx1 = *reinterpret_cast<const float4*>(xc + gy1 * 1024 + gx0);
    unsigned int mb0 = mc[(gy0 << 7) + (gx0 >> 3)];
    unsigned int mb1 = mc[(gy1 << 7) + (gx0 >> 3)];
    unsigned short dsA = *reinterpret_cast<const unsigned short*>(d_small + ((gy0 >> 1) << 9) + (gx0 >> 1));
    unsigned short dsB = *reinterpret_cast<const unsigned short*>(d_small + ((gy1 >> 1) << 9) + (gx0 >> 1));

    // halo: 576 groups = hA (all 512 threads) + hB (tid<64 -> h = tid+512)
    int aly, alxg, bly, blxg;
    halo_map(tid, aly, alxg);
    const bool hasB = (tid < 64);
    halo_map(hasB ? tid + 512 : 0, bly, blxg);
    int agy  = by0 - HALO + aly,  agx0 = bx0 - HALO + alxg * 4;
    int bgy  = by0 - HALO + bly,  bgx0 = bx0 - HALO + blxg * 4;
    bool ain = ((unsigned)agy < 1024u) & ((unsigned)agx0 < 1024u);
    bool bin = hasB & ((unsigned)bgy < 1024u) & ((unsigned)bgx0 < 1024u);
    float4 axx = make_float4(0.f, 0.f, 0.f, 0.f), bxx = axx;
    unsigned int amb = 0, bmb = 0; unsigned short ads = 0, bds = 0;
    if (ain) {
        int gi = agy * 1024 + agx0;
        axx = *reinterpret_cast<const float4*>(xc + gi);
        amb = mc[(agy << 7) + (agx0 >> 3)];
        ads = *reinterpret_cast<const unsigned short*>(d_small + ((agy >> 1) << 9) + (agx0 >> 1));
    }
    if (bin) {
        int gi = bgy * 1024 + bgx0;
        bxx = *reinterpret_cast<const float4*>(xc + gi);
        bmb = mc[(bgy << 7) + (bgx0 >> 3)];
        bds = *reinterpret_cast<const unsigned short*>(d_small + ((bgy >> 1) << 9) + (bgx0 >> 1));
    }

    // ---- encode + LDS writes (v = x unconditionally); collect nibbles ----
    unsigned int fN0, fN1, fNA = 0, fNB = 0;   // fillable nibbles
    unsigned int iN0, iN1, iNA = 0, iNB = 0;   // invalid nibbles
    int P0i0, P0i1, P0A, P0B;
    {
        unsigned int nib = (mb0 >> (gx0 & 7)) & 0xfu;
        unsigned int db = ((dsA & 0xffu) ? 0x3u : 0u) | ((dsA & 0xff00u) ? 0xcu : 0u);
        unsigned int src = db & ~nib & 0xfu;
        if (cornerTile && ((gy0 == 0) | (gy0 == 1023)))
            src |= (gx0 == 0 ? 1u : 0u) | (gx0 == 1020 ? 8u : 0u);
        P0i0 = (9 + r0) * PRW + 12 + cg0 * 4;
        *reinterpret_cast<float4*>(&v[P0i0]) = xx0;
        w32[P0i0 >> 2] = enc_w(src, nib);
        fN0 = ~src & 0xfu; iN0 = nib;
    }
    {
        unsigned int nib = (mb1 >> (gx0 & 7)) & 0xfu;
        unsigned int db = ((dsB & 0xffu) ? 0x3u : 0u) | ((dsB & 0xff00u) ? 0xcu : 0u);
        unsigned int src = db & ~nib & 0xfu;
        if (cornerTile && ((gy1 == 0) | (gy1 == 1023)))
            src |= (gx0 == 0 ? 1u : 0u) | (gx0 == 1020 ? 8u : 0u);
        P0i1 = (9 + r0 + 32) * PRW + 12 + cg0 * 4;
        *reinterpret_cast<float4*>(&v[P0i1]) = xx1;
        w32[P0i1 >> 2] = enc_w(src, nib);
        fN1 = ~src & 0xfu; iN1 = nib;
    }
    {   // halo A (all threads)
        P0A = (aly + 1) * PRW + 4 + alxg * 4;
        unsigned int ww = 0x7f7f7f7fu;
        if (ain) {
            unsigned int nib = (amb >> (agx0 & 7)) & 0xfu;
            unsigned int db = ((ads & 0xffu) ? 0x3u : 0u) | ((ads & 0xff00u) ? 0xcu : 0u);
            unsigned int src = db & ~nib & 0xfu;     // corners never in halo
            ww = enc_w(src, nib);
            fNA = ~src & 0xfu; iNA = nib;
        }
        *reinterpret_cast<float4*>(&v[P0A]) = axx;   // 0 if out-of-image (never read)
        w32[P0A >> 2] = ww;
    }
    P0B = (bly + 1) * PRW + 4 + blxg * 4;
    if (hasB) {   // halo B (tid < 64)
        unsigned int ww = 0x7f7f7f7fu;
        if (bin) {
            unsigned int nib = (bmb >> (bgx0 & 7)) & 0xfu;
            unsigned int db = ((bds & 0xffu) ? 0x3u : 0u) | ((bds & 0xff00u) ? 0xcu : 0u);
            unsigned int src = db & ~nib & 0xfu;
            ww = enc_w(src, nib);
            fNB = ~src & 0xfu; iNB = nib;
        }
        *reinterpret_cast<float4*>(&v[P0B]) = bxx;
        w32[P0B >> 2] = ww;
    }

    // ---- wave-compacted worklist build (prefix-sum + 1 atomic per wave) ----
    int cnt = __popc(fN0) + __popc(fN1) + __popc(fNA) + __popc(fNB);
    int lane = tid & 63;
    int xsum = cnt;
#pragma unroll
    for (int d = 1; d < 64; d <<= 1) {
        int y = __shfl_up(xsum, d, 64);
        if (lane >= d) xsum += y;
    }
    int base = 0;
    if (lane == 63) base = atomicAdd(&qn, xsum);
    base = __shfl(base, 63, 64);
    int idx = base + (xsum - cnt);
#define PUSH(m_, iv_, pd_, gp_) { unsigned int m = (m_); while (m) {            \
        int b = __builtin_ctz(m); m &= m - 1;                                   \
        unsigned int e = (unsigned int)((gp_) + b) | ((((iv_) >> b) & 1u) << 14)\
                         | ((((pd_) >> b) & 1u) << 15);                         \
        if (idx < QCAP) q[idx] = (unsigned short)e; ++idx; } }
    PUSH(fN0, iN0, fN0 & iN0, P0i0)        // interior: pend = fillable & invalid
    PUSH(fN1, iN1, fN1 & iN1, P0i1)
    PUSH(fNA, iNA, 0u, P0A)                // halo: never pend-relevant
    PUSH(fNB, iNB, 0u, P0B)
#undef PUSH
    __syncthreads();

    // ---- corner patch: forced-source invalid corner must have v=0 (ref fixup) ----
    if (cornerTile) {
        if (tid == 0) {
            int gy = (blockIdx.y == 0) ? 0 : 1023;
            int gx = (blockIdx.x == 0) ? 0 : 1023;
            int p = (9 + (gy - by0)) * PRW + 12 + (gx - bx0);
            if ((mc[(gy << 7) + (gx >> 3)] >> (gx & 7)) & 1u) v[p] = 0.0f;
        }
        __syncthreads();
    }

    const int n = qn;
    if (n <= QCAP) {
        // ---- worklist Jacobi: 1 px/lane, packed; skip filled via state byte ----
        for (int it = 0; it < 8; ++it) {
            int chg = 0, pend = 0;
            unsigned int thr = (unsigned int)it;
            for (int i = tid; i < n; i += 512) {
                unsigned int e = q[i];
                int p = e & 0x1fffu;
                if (w[p] & 0x7fu) continue;            // already filled
                unsigned int qu = w[p - PRW] & 0x7fu;
                unsigned int qd = w[p + PRW] & 0x7fu;
                unsigned int ql = w[p - 1]   & 0x7fu;
                unsigned int qr = w[p + 1]   & 0x7fu;
                bool su = (qu - 1u) <= thr, sd = (qd - 1u) <= thr;
                bool sl = (ql - 1u) <= thr, sr = (qr - 1u) <= thr;
                float s = (su ? v[p - PRW] : 0.0f) + (sd ? v[p + PRW] : 0.0f)
                        + (sl ? v[p - 1]   : 0.0f) + (sr ? v[p + 1]   : 0.0f);
                int cn = (int)su + (int)sd + (int)sl + (int)sr;
                if (cn > 0) {
                    v[p] = s * rcp_cnt(cn);            // reads gated by old states
                    w[p] = (unsigned char)((((e >> 14) & 1u) << 7) | (unsigned int)(it + 2));
                    chg = 1;
                } else {
                    pend |= (int)((e >> 15) & 1u);
                }
            }
            if (chg)  chgf[it] = 1;                    // benign all-write-1 races
            if (pend) pendf[it] = 1;
            __syncthreads();
            if (chgf[it] == 0 || pendf[it] == 0) break;
        }
    } else {
        // ---- overflow fallback (~never): dense sweeps over all words ----
        for (int it = 0; it < 8; ++it) {
            int chg = 0;
            unsigned int thr = (unsigned int)it;
            for (int wp = tid; wp < PWORDS; wp += 512) {
                unsigned int cw = w32[wp];
                unsigned int st = cw & 0x7f7f7f7fu;
                if ((((st - 0x01010101u) & ~st) & 0x80808080u) == 0u) continue;
                int p0 = wp * 4;
#pragma unroll
                for (int b = 0; b < 4; ++b) {
                    if (((st >> (8 * b)) & 0x7fu) != 0u) continue;  // exact per-byte
                    int p = p0 + b;
                    unsigned int qu = w[p - PRW] & 0x7fu, qd = w[p + PRW] & 0x7fu;
                    unsigned int ql = w[p - 1] & 0x7fu,   qr = w[p + 1] & 0x7fu;
                    bool su = (qu - 1u) <= thr, sd = (qd - 1u) <= thr;
                    bool sl = (ql - 1u) <= thr, sr = (qr - 1u) <= thr;
                    float s = (su ? v[p - PRW] : 0.0f) + (sd ? v[p + PRW] : 0.0f)
                            + (sl ? v[p - 1]   : 0.0f) + (sr ? v[p + 1]   : 0.0f);
                    int cn = (int)su + (int)sd + (int)sl + (int)sr;
                    if (cn > 0) {
                        v[p] = s * rcp_cnt(cn);
                        w[p] = (unsigned char)(((cw >> (8 * b)) & 0x80u) | (unsigned int)(it + 2));
                        chg = 1;
                    }
                }
            }
            if (chg) chgf[it] = 1;
            __syncthreads();
            if (chgf[it] == 0) break;
        }
    }
    // (both Jacobi exits pass through a __syncthreads: w/v stable here)

    // ---- epilogue: one blended coalesced store of the whole interior ----
#pragma unroll
    for (int k = 0; k < 2; ++k) {
        int r  = r0 + k * 32;
        int p0 = (9 + r) * PRW + 12 + cg0 * 4;
        unsigned int cw = w32[p0 >> 2];
        float4 vv = *reinterpret_cast<const float4*>(&v[p0]);
        float4 xx = (k == 0) ? xx0 : xx1;
        float4 o;
        o.x = (cw & 0x00000080u) ? vv.x : xx.x;
        o.y = (cw & 0x00008000u) ? vv.y : xx.y;
        o.z = (cw & 0x00800000u) ? vv.z : xx.z;
        o.w = (cw & 0x80000000u) ? vv.w : xx.w;
        *reinterpret_cast<float4*>(oc + (by0 + r) * 1024 + bx0 + cg0 * 4) = o;
    }
}

extern "C" void kernel_launch(void* const* d_in, const int* in_sizes, int n_in,
                              void* d_out, int out_size, void* d_ws, size_t ws_size,
                              hipStream_t stream) {
    (void)in_sizes; (void)n_in; (void)out_size; (void)ws_size;
    const float* x      = (const float*)d_in[0];
    const float* hole_u = (const float*)d_in[1];
    float* out = (float*)d_out;
    unsigned char* u_small  = (unsigned char*)d_ws;           // 256 KiB
    unsigned char* d_small  = u_small + 262144;               // 256 KiB
    unsigned char* inv_mask = d_small + 262144;               // 2 MiB

    k_mask<<<8192, 256, 0, stream>>>(hole_u, inv_mask);       // 2M threads, 8 px each
    k_us  <<<256, 256, 0, stream>>>(inv_mask, u_small);
    k_dil <<<1024, 256, 0, stream>>>(u_small, d_small);
    dim3 grid(16, 16, 16);   // tiles_x, tiles_y, channels
    k_fill<<<grid, 512, 0, stream>>>(x, inv_mask, d_small, out);
}